// Round 14
// baseline (10253.003 us; speedup 1.0000x reference)
//
#include <hip/hip_runtime.h>

#define N_PTS 16384
#define M_CTR 4096
#define K_NBR 64
#define F_OUT 128
#define CAP   256
#define FS    68
#define NCELL 4096   // 16x16x16 Morton cells
#define NBKT  256    // 16384/64 fixed 64-point buckets

// Exact (bitwise, no-contract) squared distance matching numpy f32:
// ((dx*dx + dy*dy) + dz*dz), each op round-to-nearest.
__device__ __forceinline__ float d2_exact(float ax, float ay, float az,
                                          float bx, float by, float bz) {
  float dx = __fsub_rn(ax, bx);
  float dy = __fsub_rn(ay, by);
  float dz = __fsub_rn(az, bz);
  return __fadd_rn(__fadd_rn(__fmul_rn(dx, dx), __fmul_rn(dy, dy)),
                   __fmul_rn(dz, dz));
}

// ---- DPP wave64 reductions (verified r4-r13, absmax 0): row_shr 1/2/4/8
// then row_bcast15 (rows 1,3) + row_bcast31 (rows 2,3); lane 63 has total.
__device__ __forceinline__ float wave_max_f32(float v) {
#define DPPSTEP(ctrl, rm)                                                      \
  {                                                                            \
    int _t = __builtin_amdgcn_update_dpp(__float_as_int(v), __float_as_int(v), \
                                         ctrl, rm, 0xf, false);                \
    v = fmaxf(v, __int_as_float(_t));                                          \
  }
  DPPSTEP(0x111, 0xf) DPPSTEP(0x112, 0xf) DPPSTEP(0x114, 0xf)
  DPPSTEP(0x118, 0xf) DPPSTEP(0x142, 0xa) DPPSTEP(0x143, 0xc)
#undef DPPSTEP
  return __int_as_float(__builtin_amdgcn_readlane(__float_as_int(v), 63));
}

__device__ __forceinline__ int wave_min_i32(int v) {
#define DPPSTEP(ctrl, rm)                                                      \
  {                                                                            \
    int _t = __builtin_amdgcn_update_dpp(v, v, ctrl, rm, 0xf, false);          \
    v = min(v, _t);                                                            \
  }
  DPPSTEP(0x111, 0xf) DPPSTEP(0x112, 0xf) DPPSTEP(0x114, 0xf)
  DPPSTEP(0x118, 0xf) DPPSTEP(0x142, 0xa) DPPSTEP(0x143, 0xc)
#undef DPPSTEP
  return __builtin_amdgcn_readlane(v, 63);
}

__device__ __forceinline__ float readlane_f(float v, int ln) {
  return __int_as_float(__builtin_amdgcn_readlane(__float_as_int(v), ln));
}

// ---------------------------------------------------------------------------
// Prep 1: global bbox of pos (single block) + zero the cell histogram.
// ---------------------------------------------------------------------------
__global__ void __launch_bounds__(1024) prep_bbox_kernel(const float* __restrict__ pos,
                                                         float* __restrict__ bbox,
                                                         int* __restrict__ hist) {
  const int tid = threadIdx.x;
  __shared__ float sred[6][16];
  float mn[3] = {INFINITY, INFINITY, INFINITY};
  float mx[3] = {-INFINITY, -INFINITY, -INFINITY};
  for (int p = tid; p < N_PTS; p += 1024) {
#pragma unroll
    for (int d = 0; d < 3; ++d) {
      float v = pos[3 * p + d];
      mn[d] = fminf(mn[d], v);
      mx[d] = fmaxf(mx[d], v);
    }
  }
#pragma unroll
  for (int off = 32; off > 0; off >>= 1) {
#pragma unroll
    for (int d = 0; d < 3; ++d) {
      mn[d] = fminf(mn[d], __shfl_xor(mn[d], off));
      mx[d] = fmaxf(mx[d], __shfl_xor(mx[d], off));
    }
  }
  if ((tid & 63) == 0) {
    const int w = tid >> 6;
#pragma unroll
    for (int d = 0; d < 3; ++d) { sred[d][w] = mn[d]; sred[3 + d][w] = mx[d]; }
  }
  __syncthreads();
  if (tid == 0) {
#pragma unroll
    for (int d = 0; d < 3; ++d) {
      float a = sred[d][0], b = sred[3 + d][0];
      for (int w = 1; w < 16; ++w) { a = fminf(a, sred[d][w]); b = fmaxf(b, sred[3 + d][w]); }
      bbox[d] = a; bbox[3 + d] = b;
    }
  }
  for (int i = tid; i < NCELL; i += 1024) hist[i] = 0;
}

// ---------------------------------------------------------------------------
// Prep 2: Morton cell id per point + histogram.
// ---------------------------------------------------------------------------
__device__ __forceinline__ int spread4(int v) {
  return (v & 1) | ((v & 2) << 2) | ((v & 4) << 4) | ((v & 8) << 6);
}

__global__ void __launch_bounds__(256) prep_cell_kernel(const float* __restrict__ pos,
                                                        const float* __restrict__ bbox,
                                                        int* __restrict__ cellid,
                                                        int* __restrict__ hist) {
  const int p = blockIdx.x * 256 + threadIdx.x;
  const float x = pos[3 * p], y = pos[3 * p + 1], z = pos[3 * p + 2];
  const float x0 = bbox[0], y0 = bbox[1], z0 = bbox[2];
  const float sx = 16.0f / fmaxf(bbox[3] - x0, 1e-20f);
  const float sy = 16.0f / fmaxf(bbox[4] - y0, 1e-20f);
  const float sz = 16.0f / fmaxf(bbox[5] - z0, 1e-20f);
  int cx = min(15, (int)((x - x0) * sx));
  int cy = min(15, (int)((y - y0) * sy));
  int cz = min(15, (int)((z - z0) * sz));
  const int c = spread4(cx) | (spread4(cy) << 1) | (spread4(cz) << 2);
  cellid[p] = c;
  atomicAdd(&hist[c], 1);
}

// ---------------------------------------------------------------------------
// Prep 3: exclusive scan of 4096 cell counts -> scatter cursors.
// ---------------------------------------------------------------------------
__global__ void __launch_bounds__(1024) prep_scan_kernel(const int* __restrict__ hist,
                                                         int* __restrict__ cursor) {
  __shared__ int tsum[1024];
  const int t = threadIdx.x;
  const int v0 = hist[4 * t + 0], v1 = hist[4 * t + 1];
  const int v2 = hist[4 * t + 2], v3 = hist[4 * t + 3];
  const int s = v0 + v1 + v2 + v3;
  int acc = s;
  tsum[t] = acc;
  __syncthreads();
  for (int off = 1; off < 1024; off <<= 1) {
    int add = (t >= off) ? tsum[t - off] : 0;
    __syncthreads();
    acc += add;
    tsum[t] = acc;
    __syncthreads();
  }
  int base = acc - s;  // exclusive
  cursor[4 * t + 0] = base;
  cursor[4 * t + 1] = base + v0;
  cursor[4 * t + 2] = base + v0 + v1;
  cursor[4 * t + 3] = base + v0 + v1 + v2;
}

// ---------------------------------------------------------------------------
// Prep 4: scatter to Morton-sorted packed SoA: gxyz[dst] = (x,y,z,bits(orig)).
// ---------------------------------------------------------------------------
__global__ void __launch_bounds__(256) prep_scatter_kernel(const float* __restrict__ pos,
                                                           const int* __restrict__ cellid,
                                                           int* __restrict__ cursor,
                                                           float4* __restrict__ gxyz) {
  const int p = blockIdx.x * 256 + threadIdx.x;
  const int c = cellid[p];
  const int dst = atomicAdd(&cursor[c], 1);
  gxyz[dst] = make_float4(pos[3 * p + 0], pos[3 * p + 1], pos[3 * p + 2],
                          __int_as_float(p));
}

// ---------------------------------------------------------------------------
// Prep 5: per-bucket bbox (bucket = fixed 64-point chunk of sorted order).
// ---------------------------------------------------------------------------
__global__ void __launch_bounds__(64) prep_bktbox_kernel(const float4* __restrict__ gxyz,
                                                         float* __restrict__ gbox) {
  const int b = blockIdx.x, lane = threadIdx.x;
  const float4 q = gxyz[(b << 6) + lane];
  float mnx = q.x, mny = q.y, mnz = q.z;
  float mxx = mnx, mxy = mny, mxz = mnz;
#pragma unroll
  for (int off = 32; off > 0; off >>= 1) {
    mnx = fminf(mnx, __shfl_xor(mnx, off)); mxx = fmaxf(mxx, __shfl_xor(mxx, off));
    mny = fminf(mny, __shfl_xor(mny, off)); mxy = fmaxf(mxy, __shfl_xor(mxy, off));
    mnz = fminf(mnz, __shfl_xor(mnz, off)); mxz = fmaxf(mxz, __shfl_xor(mxz, off));
  }
  if (lane == 0) {
    gbox[b * 8 + 0] = mnx; gbox[b * 8 + 1] = mxx;
    gbox[b * 8 + 2] = mny; gbox[b * 8 + 3] = mxy;
    gbox[b * 8 + 4] = mnz; gbox[b * 8 + 5] = mxz;
    gbox[b * 8 + 6] = 0.0f; gbox[b * 8 + 7] = 0.0f;
  }
}

// ---------------------------------------------------------------------------
// FPS v12 = r12 (verified, best: 7175 us) with phase B split and the
// per-bucket arg chain deferred:
//   B pass 1: for each flagged owned bucket: ds_read_b64 (x,y) + exact d2 +
//             fmin. Independent ds_reads -> latencies overlap.
//   B pass 2: value-only 6-DPP max chain + readlane per flagged bucket
//             (~75 cyc vs 275) -> lane j caches rMax (invariant: rMax ==
//             max over lanes of md[j], maintained on every update).
//   Wave winner: value chain over cached rMax -> wmax; ballot of candidate
//             buckets (rMax==wmax, almost always 1); per candidate, select
//             md/oi/pz at jc via wave-uniform unrolled compare, then ONE
//             packed-key min chain ((oi<<6)|lane) -> (argO, winner lane);
//             min-arg across candidates preserves exact tie-breaking.
//   Record (val,argO,winZ,winPos) written by lane 0 (all values uniform);
//   single barrier; C scans 8 records + broadcast sxy read (r12 verbatim).
// Tie-breaks compose to numpy first-occurrence argmax (verified r4-r13).
// ---------------------------------------------------------------------------
__global__ void __launch_bounds__(512) fps_bucket_kernel(
    const float* __restrict__ pos, const float4* __restrict__ gxyz,
    const float* __restrict__ gbox,
    int* __restrict__ idx_out, float* __restrict__ pos_s_out,
    float* __restrict__ batch_s_out) {
  __shared__ float2 sxy[N_PTS];     // 128 KB: (x,y) per sorted point
  __shared__ float4 swrec[2][8];    // [parity][wave]: val, argO, winZ, winPos
  __shared__ int sidx[M_CTR];       // 16 KB: selected centers
  const int tid = threadIdx.x;
  const int lane = tid & 63, wave = tid >> 6;
  const int pbase = (wave << 6) + lane;  // point index of (j=0) bucket slot

  // init: sxy from gxyz; per-lane z/oi registers; md=inf
  float md[32], pz[32];
  int oi[32];
#pragma unroll
  for (int j = 0; j < 32; ++j) {
    const int p = pbase + (j << 9);  // bucket j*8+wave, slot lane
    const float4 q = gxyz[p];
    pz[j] = q.z;
    oi[j] = __float_as_int(q.w);
    md[j] = INFINITY;
  }
  for (int i = tid; i < N_PTS; i += 512) {
    const float4 q = gxyz[i];
    sxy[i] = make_float2(q.x, q.y);
  }
  // bucket bbox in regs (lanes 0..31; lane l's bucket = l*8+wave)
  float bx0 = 0, bx1 = 0, by0 = 0, by1 = 0, bz0 = 0, bz1 = 0;
  if (lane < 32) {
    const int b8 = (((lane << 3) + wave) << 3);
    bx0 = gbox[b8 + 0]; bx1 = gbox[b8 + 1];
    by0 = gbox[b8 + 2]; by1 = gbox[b8 + 3];
    bz0 = gbox[b8 + 4]; bz1 = gbox[b8 + 5];
  }
  // lane-cached bucket value record (lane j holds bucket j*8+wave; j<32)
  float rMax = (lane < 32) ? INFINITY : -INFINITY;

  float cx = pos[0], cy = pos[1], cz = pos[2];
  int cIdx = 0;
  __syncthreads();  // init visibility (once)

  for (int t = 0; t < M_CTR; ++t) {
    if (tid == 0) sidx[t] = cIdx;  // LDS only

    // ---- Phase A: bbox lower-bound vs cached bucket max -> ballot ----
    bool flag = false;
    if (lane < 32) {
      float dx = fmaxf(fmaxf(bx0 - cx, cx - bx1), 0.0f);
      float dy = fmaxf(fmaxf(by0 - cy, cy - by1), 0.0f);
      float dz = fmaxf(fmaxf(bz0 - cz, cz - bz1), 0.0f);
      float lb = (dx * dx + dy * dy + dz * dz) * 0.99999f;  // safe lower bound
      flag = lb < rMax;
    }
    const unsigned mask = (unsigned)__ballot(flag);

    // ---- Phase B pass 1: batched fmin updates (independent ds_reads) ----
#pragma unroll
    for (int j = 0; j < 32; ++j) {
      if (mask & (1u << j)) {
        const float2 xy = sxy[pbase + (j << 9)];
        md[j] = fminf(md[j], d2_exact(xy.x, xy.y, pz[j], cx, cy, cz));
      }
    }
    // ---- Phase B pass 2: value-only bucket max chains ----
#pragma unroll
    for (int j = 0; j < 32; ++j) {
      if (mask & (1u << j)) {
        const float bmax = wave_max_f32(md[j]);
        if (lane == j) rMax = bmax;
      }
    }

    // ---- wave winner: val chain, then arg-chase for candidate bucket(s) ----
    const float wmax = wave_max_f32(rMax);
    unsigned long long cand = __ballot(rMax == wmax);  // lanes<32 only
    int warg = 0x7fffffff; float wz = 0.0f; int wpos = 0;
    while (cand) {  // almost always exactly one candidate
      const int jc = (int)__ffsll(cand) - 1;  // wave-uniform
      cand &= cand - 1;
      float mdc = 0.0f, pzc = 0.0f; int oic = 0;
#pragma unroll
      for (int j = 0; j < 32; ++j)  // uniform select (scalar branches)
        if (j == jc) { mdc = md[j]; oic = oi[j]; pzc = pz[j]; }
      // packed key: (oi<<6)|lane -> min = (min oi, its lane); oi < 2^14
      const int key = (mdc == wmax) ? ((oic << 6) | lane) : 0x7fffffff;
      const int kmin = wave_min_i32(key);
      const int a = kmin >> 6, ln = kmin & 63;
      if (a < warg) {
        warg = a;
        wz = readlane_f(pzc, ln);
        wpos = (((jc << 3) + wave) << 6) + ln;  // winner sorted position
      }
    }
    const int par = t & 1;
    if (lane == 0)  // all fields wave-uniform
      swrec[par][wave] =
          make_float4(wmax, __int_as_float(warg), wz, __int_as_float(wpos));
    __syncthreads();  // the ONLY barrier per step

    // ---- Phase C: global winner over 8 float4 records ----
    float bv = -INFINITY; int bo = 0x7fffffff;
    float bzv = 0.0f; int bp = 0;
#pragma unroll
    for (int w = 0; w < 8; ++w) {
      const float4 r = swrec[par][w];
      const int ro = __float_as_int(r.y);
      if (r.x > bv || (r.x == bv && ro < bo)) {
        bv = r.x; bo = ro; bzv = r.z; bp = __float_as_int(r.w);
      }
    }
    cIdx = bo;
    const float2 cxy = sxy[bp];  // broadcast LDS read (read-only region)
    cx = cxy.x; cy = cxy.y; cz = bzv;
    // no second barrier: next step writes swrec[par^1] (disjoint); sxy is
    // read-only; B writes no other LDS.
  }
  __syncthreads();  // sidx visible (once)
  for (int i = tid; i < M_CTR; i += 512) {
    const int si = sidx[i];
    idx_out[i] = si;
    pos_s_out[3 * i + 0] = pos[3 * si + 0];  // exact gather == pos[idx]
    pos_s_out[3 * i + 1] = pos[3 * si + 1];
    pos_s_out[3 * i + 2] = pos[3 * si + 2];
    batch_s_out[i] = 0.0f;
  }
}

// ---------------------------------------------------------------------------
// Kernel 2: radius neighbors (unchanged).
// ---------------------------------------------------------------------------
__global__ void __launch_bounds__(256) nbr_kernel(const float* __restrict__ pos,
                                                  const int* __restrict__ idx,
                                                  int* __restrict__ nbr) {
  const int m = blockIdx.x, tid = threadIdx.x;
  __shared__ int s_cnt;
  __shared__ float s_d2[CAP];
  __shared__ int s_idx[CAP];
  if (tid == 0) s_cnt = 0;
  const int cen = idx[m];
  const float cx = pos[3 * cen + 0], cy = pos[3 * cen + 1], cz = pos[3 * cen + 2];
  __syncthreads();
  const float RR = 0.04f;  // f32(python 0.2*0.2)
  for (int i = 0; i < N_PTS / 256; ++i) {
    const int p = tid + 256 * i;
    float d2 = d2_exact(pos[3 * p], pos[3 * p + 1], pos[3 * p + 2], cx, cy, cz);
    if (d2 <= RR) {
      int slot = atomicAdd(&s_cnt, 1);
      if (slot < CAP) { s_d2[slot] = d2; s_idx[slot] = p; }
    }
  }
  __syncthreads();
  const int cnt = s_cnt;
  if (cnt <= K_NBR) {
    if (tid < K_NBR) nbr[m * K_NBR + tid] = (tid < cnt) ? s_idx[tid] : cen;
  } else {
    const int n = cnt < CAP ? cnt : CAP;
    if (tid >= n) { s_d2[tid] = INFINITY; s_idx[tid] = 0x7fffffff; }
    __syncthreads();
    for (int k = 2; k <= CAP; k <<= 1) {
      for (int j = k >> 1; j > 0; j >>= 1) {
        const int ixj = tid ^ j;
        if (ixj > tid) {
          float da = s_d2[tid], db = s_d2[ixj];
          int ia = s_idx[tid], ib = s_idx[ixj];
          bool gt = (da > db) || (da == db && ia > ib);
          bool asc = ((tid & k) == 0);
          if (gt == asc) {
            s_d2[tid] = db; s_d2[ixj] = da;
            s_idx[tid] = ib; s_idx[ixj] = ia;
          }
        }
        __syncthreads();
      }
    }
    if (tid < K_NBR) nbr[m * K_NBR + tid] = s_idx[tid];
  }
}

// ---------------------------------------------------------------------------
// Kernel 3: fused gather + 3-layer MLP + max aggregation (unchanged).
// ---------------------------------------------------------------------------
__device__ __forceinline__ void mlp_layer(const float (*__restrict__ A)[FS],
                                          const float (*__restrict__ W)[64],
                                          int K, int e0, int c0, float acc[4][4]) {
#pragma unroll
  for (int j = 0; j < 4; ++j)
#pragma unroll
    for (int i = 0; i < 4; ++i) acc[j][i] = W[67][c0 + i];  // bias row
#pragma unroll 4
  for (int k = 0; k < K; ++k) {
    const float4 w = *(const float4*)&W[k][c0];
    const float a0 = A[e0 + 0][k], a1 = A[e0 + 1][k];
    const float a2 = A[e0 + 2][k], a3 = A[e0 + 3][k];
    acc[0][0] = fmaf(a0, w.x, acc[0][0]); acc[0][1] = fmaf(a0, w.y, acc[0][1]);
    acc[0][2] = fmaf(a0, w.z, acc[0][2]); acc[0][3] = fmaf(a0, w.w, acc[0][3]);
    acc[1][0] = fmaf(a1, w.x, acc[1][0]); acc[1][1] = fmaf(a1, w.y, acc[1][1]);
    acc[1][2] = fmaf(a1, w.z, acc[1][2]); acc[1][3] = fmaf(a1, w.w, acc[1][3]);
    acc[2][0] = fmaf(a2, w.x, acc[2][0]); acc[2][1] = fmaf(a2, w.y, acc[2][1]);
    acc[2][2] = fmaf(a2, w.z, acc[2][2]); acc[2][3] = fmaf(a2, w.w, acc[2][3]);
    acc[3][0] = fmaf(a3, w.x, acc[3][0]); acc[3][1] = fmaf(a3, w.y, acc[3][1]);
    acc[3][2] = fmaf(a3, w.z, acc[3][2]); acc[3][3] = fmaf(a3, w.w, acc[3][3]);
  }
#pragma unroll
  for (int j = 0; j < 4; ++j)
#pragma unroll
    for (int i = 0; i < 4; ++i) acc[j][i] = fmaxf(acc[j][i], 0.0f);
}

__global__ void __launch_bounds__(512) mlp_kernel(
    const float* __restrict__ x, const float* __restrict__ pos,
    const int* __restrict__ nbr, const float* __restrict__ pos_s,
    const float* __restrict__ W1, const float* __restrict__ b1,
    const float* __restrict__ W2, const float* __restrict__ b2,
    const float* __restrict__ W3, const float* __restrict__ b3,
    float* __restrict__ out) {
  __shared__ float Fb[2][64][FS];
  __shared__ float Wb[FS][64];
  __shared__ float Pb[2][16][64];
  __shared__ int s_nbr[128];
  const int t = threadIdx.x;
  const int m0 = blockIdx.x * 2;

  if (t < 128) s_nbr[t] = nbr[m0 * K_NBR + t];
  __syncthreads();

  {
    const int ge = t >> 2, wch = ge >> 6, e = ge & 63, c16 = (t & 3) * 16;
    const int n = s_nbr[ge];
    const float4* src = (const float4*)(x + n * 64 + c16);
    float4* dst = (float4*)(&Fb[wch][e][c16]);
    dst[0] = src[0]; dst[1] = src[1]; dst[2] = src[2]; dst[3] = src[3];
  }
  if (t < 128) {
    const int wch = t >> 6, e = t & 63;
    const int n = s_nbr[t];
    const float cx = pos_s[(m0 + wch) * 3 + 0];
    const float cy = pos_s[(m0 + wch) * 3 + 1];
    const float cz = pos_s[(m0 + wch) * 3 + 2];
    Fb[wch][e][64] = pos[3 * n + 0] - cx;
    Fb[wch][e][65] = pos[3 * n + 1] - cy;
    Fb[wch][e][66] = pos[3 * n + 2] - cz;
    Fb[wch][e][67] = 0.0f;
  }
  for (int i = t; i < 67 * 64; i += 512) ((float*)Wb)[i] = W1[i];
  if (t < 64) Wb[67][t] = b1[t];
  __syncthreads();

  const int wch = t >> 8, tt = t & 255;
  const int e0 = (tt >> 4) << 2, c0 = (tt & 15) << 2;
  float acc[4][4];

  mlp_layer(Fb[wch], Wb, 67, e0, c0, acc);
  __syncthreads();
#pragma unroll
  for (int j = 0; j < 4; ++j)
#pragma unroll
    for (int i = 0; i < 4; ++i) Fb[wch][e0 + j][c0 + i] = acc[j][i];
  for (int i = t; i < 64 * 64; i += 512) ((float*)Wb)[i] = W2[i];
  if (t < 64) Wb[67][t] = b2[t];
  __syncthreads();

  mlp_layer(Fb[wch], Wb, 64, e0, c0, acc);
  __syncthreads();
#pragma unroll
  for (int j = 0; j < 4; ++j)
#pragma unroll
    for (int i = 0; i < 4; ++i) Fb[wch][e0 + j][c0 + i] = acc[j][i];

  for (int h = 0; h < 2; ++h) {
    for (int i = t; i < 64 * 64; i += 512)
      ((float*)Wb)[i] = W3[(i >> 6) * 128 + h * 64 + (i & 63)];
    if (t < 64) Wb[67][t] = b3[h * 64 + t];
    __syncthreads();
    mlp_layer(Fb[wch], Wb, 64, e0, c0, acc);
#pragma unroll
    for (int i = 0; i < 4; ++i) {
      float v = fmaxf(fmaxf(acc[0][i], acc[1][i]), fmaxf(acc[2][i], acc[3][i]));
      Pb[wch][tt >> 4][c0 + i] = v;
    }
    __syncthreads();
    if (tt < 64) {
      float v = Pb[wch][0][tt];
#pragma unroll
      for (int r = 1; r < 16; ++r) v = fmaxf(v, Pb[wch][r][tt]);
      out[(m0 + wch) * F_OUT + h * 64 + tt] = v;
    }
    __syncthreads();
  }
}

// ---------------------------------------------------------------------------
extern "C" void kernel_launch(void* const* d_in, const int* in_sizes, int n_in,
                              void* d_out, int out_size, void* d_ws, size_t ws_size,
                              hipStream_t stream) {
  const float* x   = (const float*)d_in[0];
  const float* pos = (const float*)d_in[1];
  const float* W1 = (const float*)d_in[3];
  const float* b1 = (const float*)d_in[4];
  const float* W2 = (const float*)d_in[5];
  const float* b2 = (const float*)d_in[6];
  const float* W3 = (const float*)d_in[7];
  const float* b3 = (const float*)d_in[8];

  float* out     = (float*)d_out;                 // [M,128]
  float* pos_s   = out + M_CTR * F_OUT;           // [M,3]
  float* batch_s = pos_s + M_CTR * 3;             // [M]

  // workspace layout (gxyz offset 16B-aligned)
  int*    idx    = (int*)d_ws;                    // 4096
  int*    nbr    = idx + M_CTR;                   // 4096*64
  float*  bbox   = (float*)(nbr + M_CTR * K_NBR); // 8
  int*    hist   = (int*)(bbox + 8);              // 4096
  int*    cursor = hist + NCELL;                  // 4096
  int*    cellid = cursor + NCELL;                // 16384
  float4* gxyz   = (float4*)(cellid + N_PTS);     // 16384 float4
  float*  gbox   = (float*)(gxyz + N_PTS);        // 256*8

  prep_bbox_kernel<<<1, 1024, 0, stream>>>(pos, bbox, hist);
  prep_cell_kernel<<<N_PTS / 256, 256, 0, stream>>>(pos, bbox, cellid, hist);
  prep_scan_kernel<<<1, 1024, 0, stream>>>(hist, cursor);
  prep_scatter_kernel<<<N_PTS / 256, 256, 0, stream>>>(pos, cellid, cursor, gxyz);
  prep_bktbox_kernel<<<NBKT, 64, 0, stream>>>(gxyz, gbox);
  fps_bucket_kernel<<<1, 512, 0, stream>>>(pos, gxyz, gbox, idx, pos_s, batch_s);
  nbr_kernel<<<M_CTR, 256, 0, stream>>>(pos, idx, nbr);
  mlp_kernel<<<M_CTR / 2, 512, 0, stream>>>(x, pos, nbr, pos_s,
                                            W1, b1, W2, b2, W3, b3, out);
}

// Round 15
// 7261.378 us; speedup vs baseline: 1.4120x; 1.4120x over previous
//
#include <hip/hip_runtime.h>

#define N_PTS 16384
#define M_CTR 4096
#define K_NBR 64
#define F_OUT 128
#define CAP   256
#define FS    68
#define NCELL 4096   // 16x16x16 Morton cells
#define NBKT  256    // 16384/64 fixed 64-point buckets

// Exact (bitwise, no-contract) squared distance matching numpy f32:
// ((dx*dx + dy*dy) + dz*dz), each op round-to-nearest.
__device__ __forceinline__ float d2_exact(float ax, float ay, float az,
                                          float bx, float by, float bz) {
  float dx = __fsub_rn(ax, bx);
  float dy = __fsub_rn(ay, by);
  float dz = __fsub_rn(az, bz);
  return __fadd_rn(__fadd_rn(__fmul_rn(dx, dx), __fmul_rn(dy, dy)),
                   __fmul_rn(dz, dz));
}

// ---- DPP wave64 reductions (verified r4-r14, absmax 0): row_shr 1/2/4/8
// then row_bcast15 (rows 1,3) + row_bcast31 (rows 2,3); lane 63 has total.
__device__ __forceinline__ float wave_max_f32(float v) {
#define DPPSTEP(ctrl, rm)                                                      \
  {                                                                            \
    int _t = __builtin_amdgcn_update_dpp(__float_as_int(v), __float_as_int(v), \
                                         ctrl, rm, 0xf, false);                \
    v = fmaxf(v, __int_as_float(_t));                                          \
  }
  DPPSTEP(0x111, 0xf) DPPSTEP(0x112, 0xf) DPPSTEP(0x114, 0xf)
  DPPSTEP(0x118, 0xf) DPPSTEP(0x142, 0xa) DPPSTEP(0x143, 0xc)
#undef DPPSTEP
  return __int_as_float(__builtin_amdgcn_readlane(__float_as_int(v), 63));
}

__device__ __forceinline__ int wave_min_i32(int v) {
#define DPPSTEP(ctrl, rm)                                                      \
  {                                                                            \
    int _t = __builtin_amdgcn_update_dpp(v, v, ctrl, rm, 0xf, false);          \
    v = min(v, _t);                                                            \
  }
  DPPSTEP(0x111, 0xf) DPPSTEP(0x112, 0xf) DPPSTEP(0x114, 0xf)
  DPPSTEP(0x118, 0xf) DPPSTEP(0x142, 0xa) DPPSTEP(0x143, 0xc)
#undef DPPSTEP
  return __builtin_amdgcn_readlane(v, 63);
}

__device__ __forceinline__ float readlane_f(float v, int ln) {
  return __int_as_float(__builtin_amdgcn_readlane(__float_as_int(v), ln));
}

// ---------------------------------------------------------------------------
// Prep 1: global bbox of pos (single block) + zero the cell histogram.
// ---------------------------------------------------------------------------
__global__ void __launch_bounds__(1024) prep_bbox_kernel(const float* __restrict__ pos,
                                                         float* __restrict__ bbox,
                                                         int* __restrict__ hist) {
  const int tid = threadIdx.x;
  __shared__ float sred[6][16];
  float mn[3] = {INFINITY, INFINITY, INFINITY};
  float mx[3] = {-INFINITY, -INFINITY, -INFINITY};
  for (int p = tid; p < N_PTS; p += 1024) {
#pragma unroll
    for (int d = 0; d < 3; ++d) {
      float v = pos[3 * p + d];
      mn[d] = fminf(mn[d], v);
      mx[d] = fmaxf(mx[d], v);
    }
  }
#pragma unroll
  for (int off = 32; off > 0; off >>= 1) {
#pragma unroll
    for (int d = 0; d < 3; ++d) {
      mn[d] = fminf(mn[d], __shfl_xor(mn[d], off));
      mx[d] = fmaxf(mx[d], __shfl_xor(mx[d], off));
    }
  }
  if ((tid & 63) == 0) {
    const int w = tid >> 6;
#pragma unroll
    for (int d = 0; d < 3; ++d) { sred[d][w] = mn[d]; sred[3 + d][w] = mx[d]; }
  }
  __syncthreads();
  if (tid == 0) {
#pragma unroll
    for (int d = 0; d < 3; ++d) {
      float a = sred[d][0], b = sred[3 + d][0];
      for (int w = 1; w < 16; ++w) { a = fminf(a, sred[d][w]); b = fmaxf(b, sred[3 + d][w]); }
      bbox[d] = a; bbox[3 + d] = b;
    }
  }
  for (int i = tid; i < NCELL; i += 1024) hist[i] = 0;
}

// ---------------------------------------------------------------------------
// Prep 2: Morton cell id per point + histogram.
// ---------------------------------------------------------------------------
__device__ __forceinline__ int spread4(int v) {
  return (v & 1) | ((v & 2) << 2) | ((v & 4) << 4) | ((v & 8) << 6);
}

__global__ void __launch_bounds__(256) prep_cell_kernel(const float* __restrict__ pos,
                                                        const float* __restrict__ bbox,
                                                        int* __restrict__ cellid,
                                                        int* __restrict__ hist) {
  const int p = blockIdx.x * 256 + threadIdx.x;
  const float x = pos[3 * p], y = pos[3 * p + 1], z = pos[3 * p + 2];
  const float x0 = bbox[0], y0 = bbox[1], z0 = bbox[2];
  const float sx = 16.0f / fmaxf(bbox[3] - x0, 1e-20f);
  const float sy = 16.0f / fmaxf(bbox[4] - y0, 1e-20f);
  const float sz = 16.0f / fmaxf(bbox[5] - z0, 1e-20f);
  int cx = min(15, (int)((x - x0) * sx));
  int cy = min(15, (int)((y - y0) * sy));
  int cz = min(15, (int)((z - z0) * sz));
  const int c = spread4(cx) | (spread4(cy) << 1) | (spread4(cz) << 2);
  cellid[p] = c;
  atomicAdd(&hist[c], 1);
}

// ---------------------------------------------------------------------------
// Prep 3: exclusive scan of 4096 cell counts -> scatter cursors.
// ---------------------------------------------------------------------------
__global__ void __launch_bounds__(1024) prep_scan_kernel(const int* __restrict__ hist,
                                                         int* __restrict__ cursor) {
  __shared__ int tsum[1024];
  const int t = threadIdx.x;
  const int v0 = hist[4 * t + 0], v1 = hist[4 * t + 1];
  const int v2 = hist[4 * t + 2], v3 = hist[4 * t + 3];
  const int s = v0 + v1 + v2 + v3;
  int acc = s;
  tsum[t] = acc;
  __syncthreads();
  for (int off = 1; off < 1024; off <<= 1) {
    int add = (t >= off) ? tsum[t - off] : 0;
    __syncthreads();
    acc += add;
    tsum[t] = acc;
    __syncthreads();
  }
  int base = acc - s;  // exclusive
  cursor[4 * t + 0] = base;
  cursor[4 * t + 1] = base + v0;
  cursor[4 * t + 2] = base + v0 + v1;
  cursor[4 * t + 3] = base + v0 + v1 + v2;
}

// ---------------------------------------------------------------------------
// Prep 4: scatter to Morton-sorted packed SoA: gxyz[dst] = (x,y,z,bits(orig)).
// ---------------------------------------------------------------------------
__global__ void __launch_bounds__(256) prep_scatter_kernel(const float* __restrict__ pos,
                                                           const int* __restrict__ cellid,
                                                           int* __restrict__ cursor,
                                                           float4* __restrict__ gxyz) {
  const int p = blockIdx.x * 256 + threadIdx.x;
  const int c = cellid[p];
  const int dst = atomicAdd(&cursor[c], 1);
  gxyz[dst] = make_float4(pos[3 * p + 0], pos[3 * p + 1], pos[3 * p + 2],
                          __int_as_float(p));
}

// ---------------------------------------------------------------------------
// Prep 5: per-bucket bbox (bucket = fixed 64-point chunk of sorted order).
// ---------------------------------------------------------------------------
__global__ void __launch_bounds__(64) prep_bktbox_kernel(const float4* __restrict__ gxyz,
                                                         float* __restrict__ gbox) {
  const int b = blockIdx.x, lane = threadIdx.x;
  const float4 q = gxyz[(b << 6) + lane];
  float mnx = q.x, mny = q.y, mnz = q.z;
  float mxx = mnx, mxy = mny, mxz = mnz;
#pragma unroll
  for (int off = 32; off > 0; off >>= 1) {
    mnx = fminf(mnx, __shfl_xor(mnx, off)); mxx = fmaxf(mxx, __shfl_xor(mxx, off));
    mny = fminf(mny, __shfl_xor(mny, off)); mxy = fmaxf(mxy, __shfl_xor(mxy, off));
    mnz = fminf(mnz, __shfl_xor(mnz, off)); mxz = fmaxf(mxz, __shfl_xor(mxz, off));
  }
  if (lane == 0) {
    gbox[b * 8 + 0] = mnx; gbox[b * 8 + 1] = mxx;
    gbox[b * 8 + 2] = mny; gbox[b * 8 + 3] = mxy;
    gbox[b * 8 + 4] = mnz; gbox[b * 8 + 5] = mxz;
    gbox[b * 8 + 6] = 0.0f; gbox[b * 8 + 7] = 0.0f;
  }
}

// ---------------------------------------------------------------------------
// FPS v13 = r12 verbatim (best measured: 7175 us fps, absmax 0.0) with one
// verified micro-change: the per-bucket arg reduction uses the packed key
// (oi<<6)|lane (r13-verified) -> lexicographic min gives (min orig idx, its
// lane) in ONE chain, removing the per-bucket ballot+ffsll. Everything else
// identical to r12: 8 waves, (x,y) in LDS (read-only after init), z/md/oi
// in registers (compile-time j), single barrier per step via parity-
// disjoint records, zero global memory ops inside the step loop.
// Tie-breaks compose to numpy first-occurrence argmax (verified r4-r14).
// ---------------------------------------------------------------------------
__global__ void __launch_bounds__(512) fps_bucket_kernel(
    const float* __restrict__ pos, const float4* __restrict__ gxyz,
    const float* __restrict__ gbox,
    int* __restrict__ idx_out, float* __restrict__ pos_s_out,
    float* __restrict__ batch_s_out) {
  __shared__ float2 sxy[N_PTS];     // 128 KB: (x,y) per sorted point
  __shared__ float4 swrec[2][8];    // [parity][wave]: val, argO, winZ, winPos
  __shared__ int sidx[M_CTR];       // 16 KB: selected centers
  const int tid = threadIdx.x;
  const int lane = tid & 63, wave = tid >> 6;
  const int pbase = (wave << 6) + lane;  // point index of (j=0) bucket slot

  // init: sxy from gxyz; per-lane z/oi registers; md=inf
  float md[32], pz[32];
  int oi[32];
#pragma unroll
  for (int j = 0; j < 32; ++j) {
    const int p = pbase + (j << 9);  // bucket j*8+wave, slot lane
    const float4 q = gxyz[p];
    pz[j] = q.z;
    oi[j] = __float_as_int(q.w);
    md[j] = INFINITY;
  }
  for (int i = tid; i < N_PTS; i += 512) {
    const float4 q = gxyz[i];
    sxy[i] = make_float2(q.x, q.y);
  }
  // bucket bbox in regs (lanes 0..31; lane l's bucket = l*8+wave)
  float bx0 = 0, bx1 = 0, by0 = 0, by1 = 0, bz0 = 0, bz1 = 0;
  if (lane < 32) {
    const int b8 = (((lane << 3) + wave) << 3);
    bx0 = gbox[b8 + 0]; bx1 = gbox[b8 + 1];
    by0 = gbox[b8 + 2]; by1 = gbox[b8 + 3];
    bz0 = gbox[b8 + 4]; bz1 = gbox[b8 + 5];
  }
  // lane-cached bucket record (lane j holds bucket j*8+wave; j<32)
  float rMax = (lane < 32) ? INFINITY : -INFINITY;
  int rArg = 0x7fffffff;
  float rZ = 0.0f;
  int rPos = 0;

  float cx = pos[0], cy = pos[1], cz = pos[2];
  int cIdx = 0;
  __syncthreads();  // init visibility (once)

  for (int t = 0; t < M_CTR; ++t) {
    if (tid == 0) sidx[t] = cIdx;  // LDS only

    // ---- Phase A: bbox lower-bound vs cached bucket max -> ballot ----
    bool flag = false;
    if (lane < 32) {
      float dx = fmaxf(fmaxf(bx0 - cx, cx - bx1), 0.0f);
      float dy = fmaxf(fmaxf(by0 - cy, cy - by1), 0.0f);
      float dz = fmaxf(fmaxf(bz0 - cz, cz - bz1), 0.0f);
      float lb = (dx * dx + dy * dy + dz * dz) * 0.99999f;  // safe lower bound
      flag = lb < rMax;
    }
    const unsigned mask = (unsigned)__ballot(flag);

    // ---- Phase B: update flagged owned buckets (LDS coords, reg state) ----
#pragma unroll
    for (int j = 0; j < 32; ++j) {
      if (mask & (1u << j)) {
        const int p = pbase + (j << 9);
        const float2 xy = sxy[p];                       // ds_read_b64
        const float d2v = d2_exact(xy.x, xy.y, pz[j], cx, cy, cz);
        md[j] = fminf(md[j], d2v);
        const float bmax = wave_max_f32(md[j]);
        // packed key: (oi<<6)|lane -> min = (min oi, its lane); oi < 2^14
        const int key = (md[j] == bmax) ? ((oi[j] << 6) | lane) : 0x7fffffff;
        const int kmin = wave_min_i32(key);
        const int barg = kmin >> 6;
        const int ln = kmin & 63;
        const float wz = readlane_f(pz[j], ln);
        if (lane == j) {
          rMax = bmax; rArg = barg; rZ = wz;
          rPos = ((((j << 3) + wave)) << 6) + ln;       // winner sorted pos
        }
      }
    }

    // ---- wave winner over 32 lane-records (lanes>=32 hold -inf) ----
    const float wmax = wave_max_f32(rMax);
    const int warg = wave_min_i32(rMax == wmax ? rArg : 0x7fffffff);
    const int par = t & 1;
    if (rArg == warg) {  // exactly one lane (orig indices unique)
      swrec[par][wave] =
          make_float4(rMax, __int_as_float(rArg), rZ, __int_as_float(rPos));
    }
    __syncthreads();  // the ONLY barrier per step

    // ---- Phase C: global winner over 8 float4 records ----
    float bv = -INFINITY; int bo = 0x7fffffff;
    float bzv = 0.0f; int bp = 0;
#pragma unroll
    for (int w = 0; w < 8; ++w) {
      const float4 r = swrec[par][w];
      const int ro = __float_as_int(r.y);
      if (r.x > bv || (r.x == bv && ro < bo)) {
        bv = r.x; bo = ro; bzv = r.z; bp = __float_as_int(r.w);
      }
    }
    cIdx = bo;
    const float2 cxy = sxy[bp];  // broadcast LDS read (read-only region)
    cx = cxy.x; cy = cxy.y; cz = bzv;
    // no second barrier: next step writes swrec[par^1] (disjoint); sxy is
    // read-only; B writes no other LDS.
  }
  __syncthreads();  // sidx visible (once)
  for (int i = tid; i < M_CTR; i += 512) {
    const int si = sidx[i];
    idx_out[i] = si;
    pos_s_out[3 * i + 0] = pos[3 * si + 0];  // exact gather == pos[idx]
    pos_s_out[3 * i + 1] = pos[3 * si + 1];
    pos_s_out[3 * i + 2] = pos[3 * si + 2];
    batch_s_out[i] = 0.0f;
  }
}

// ---------------------------------------------------------------------------
// Kernel 2: radius neighbors (unchanged).
// ---------------------------------------------------------------------------
__global__ void __launch_bounds__(256) nbr_kernel(const float* __restrict__ pos,
                                                  const int* __restrict__ idx,
                                                  int* __restrict__ nbr) {
  const int m = blockIdx.x, tid = threadIdx.x;
  __shared__ int s_cnt;
  __shared__ float s_d2[CAP];
  __shared__ int s_idx[CAP];
  if (tid == 0) s_cnt = 0;
  const int cen = idx[m];
  const float cx = pos[3 * cen + 0], cy = pos[3 * cen + 1], cz = pos[3 * cen + 2];
  __syncthreads();
  const float RR = 0.04f;  // f32(python 0.2*0.2)
  for (int i = 0; i < N_PTS / 256; ++i) {
    const int p = tid + 256 * i;
    float d2 = d2_exact(pos[3 * p], pos[3 * p + 1], pos[3 * p + 2], cx, cy, cz);
    if (d2 <= RR) {
      int slot = atomicAdd(&s_cnt, 1);
      if (slot < CAP) { s_d2[slot] = d2; s_idx[slot] = p; }
    }
  }
  __syncthreads();
  const int cnt = s_cnt;
  if (cnt <= K_NBR) {
    if (tid < K_NBR) nbr[m * K_NBR + tid] = (tid < cnt) ? s_idx[tid] : cen;
  } else {
    const int n = cnt < CAP ? cnt : CAP;
    if (tid >= n) { s_d2[tid] = INFINITY; s_idx[tid] = 0x7fffffff; }
    __syncthreads();
    for (int k = 2; k <= CAP; k <<= 1) {
      for (int j = k >> 1; j > 0; j >>= 1) {
        const int ixj = tid ^ j;
        if (ixj > tid) {
          float da = s_d2[tid], db = s_d2[ixj];
          int ia = s_idx[tid], ib = s_idx[ixj];
          bool gt = (da > db) || (da == db && ia > ib);
          bool asc = ((tid & k) == 0);
          if (gt == asc) {
            s_d2[tid] = db; s_d2[ixj] = da;
            s_idx[tid] = ib; s_idx[ixj] = ia;
          }
        }
        __syncthreads();
      }
    }
    if (tid < K_NBR) nbr[m * K_NBR + tid] = s_idx[tid];
  }
}

// ---------------------------------------------------------------------------
// Kernel 3: fused gather + 3-layer MLP + max aggregation (unchanged).
// ---------------------------------------------------------------------------
__device__ __forceinline__ void mlp_layer(const float (*__restrict__ A)[FS],
                                          const float (*__restrict__ W)[64],
                                          int K, int e0, int c0, float acc[4][4]) {
#pragma unroll
  for (int j = 0; j < 4; ++j)
#pragma unroll
    for (int i = 0; i < 4; ++i) acc[j][i] = W[67][c0 + i];  // bias row
#pragma unroll 4
  for (int k = 0; k < K; ++k) {
    const float4 w = *(const float4*)&W[k][c0];
    const float a0 = A[e0 + 0][k], a1 = A[e0 + 1][k];
    const float a2 = A[e0 + 2][k], a3 = A[e0 + 3][k];
    acc[0][0] = fmaf(a0, w.x, acc[0][0]); acc[0][1] = fmaf(a0, w.y, acc[0][1]);
    acc[0][2] = fmaf(a0, w.z, acc[0][2]); acc[0][3] = fmaf(a0, w.w, acc[0][3]);
    acc[1][0] = fmaf(a1, w.x, acc[1][0]); acc[1][1] = fmaf(a1, w.y, acc[1][1]);
    acc[1][2] = fmaf(a1, w.z, acc[1][2]); acc[1][3] = fmaf(a1, w.w, acc[1][3]);
    acc[2][0] = fmaf(a2, w.x, acc[2][0]); acc[2][1] = fmaf(a2, w.y, acc[2][1]);
    acc[2][2] = fmaf(a2, w.z, acc[2][2]); acc[2][3] = fmaf(a2, w.w, acc[2][3]);
    acc[3][0] = fmaf(a3, w.x, acc[3][0]); acc[3][1] = fmaf(a3, w.y, acc[3][1]);
    acc[3][2] = fmaf(a3, w.z, acc[3][2]); acc[3][3] = fmaf(a3, w.w, acc[3][3]);
  }
#pragma unroll
  for (int j = 0; j < 4; ++j)
#pragma unroll
    for (int i = 0; i < 4; ++i) acc[j][i] = fmaxf(acc[j][i], 0.0f);
}

__global__ void __launch_bounds__(512) mlp_kernel(
    const float* __restrict__ x, const float* __restrict__ pos,
    const int* __restrict__ nbr, const float* __restrict__ pos_s,
    const float* __restrict__ W1, const float* __restrict__ b1,
    const float* __restrict__ W2, const float* __restrict__ b2,
    const float* __restrict__ W3, const float* __restrict__ b3,
    float* __restrict__ out) {
  __shared__ float Fb[2][64][FS];
  __shared__ float Wb[FS][64];
  __shared__ float Pb[2][16][64];
  __shared__ int s_nbr[128];
  const int t = threadIdx.x;
  const int m0 = blockIdx.x * 2;

  if (t < 128) s_nbr[t] = nbr[m0 * K_NBR + t];
  __syncthreads();

  {
    const int ge = t >> 2, wch = ge >> 6, e = ge & 63, c16 = (t & 3) * 16;
    const int n = s_nbr[ge];
    const float4* src = (const float4*)(x + n * 64 + c16);
    float4* dst = (float4*)(&Fb[wch][e][c16]);
    dst[0] = src[0]; dst[1] = src[1]; dst[2] = src[2]; dst[3] = src[3];
  }
  if (t < 128) {
    const int wch = t >> 6, e = t & 63;
    const int n = s_nbr[t];
    const float cx = pos_s[(m0 + wch) * 3 + 0];
    const float cy = pos_s[(m0 + wch) * 3 + 1];
    const float cz = pos_s[(m0 + wch) * 3 + 2];
    Fb[wch][e][64] = pos[3 * n + 0] - cx;
    Fb[wch][e][65] = pos[3 * n + 1] - cy;
    Fb[wch][e][66] = pos[3 * n + 2] - cz;
    Fb[wch][e][67] = 0.0f;
  }
  for (int i = t; i < 67 * 64; i += 512) ((float*)Wb)[i] = W1[i];
  if (t < 64) Wb[67][t] = b1[t];
  __syncthreads();

  const int wch = t >> 8, tt = t & 255;
  const int e0 = (tt >> 4) << 2, c0 = (tt & 15) << 2;
  float acc[4][4];

  mlp_layer(Fb[wch], Wb, 67, e0, c0, acc);
  __syncthreads();
#pragma unroll
  for (int j = 0; j < 4; ++j)
#pragma unroll
    for (int i = 0; i < 4; ++i) Fb[wch][e0 + j][c0 + i] = acc[j][i];
  for (int i = t; i < 64 * 64; i += 512) ((float*)Wb)[i] = W2[i];
  if (t < 64) Wb[67][t] = b2[t];
  __syncthreads();

  mlp_layer(Fb[wch], Wb, 64, e0, c0, acc);
  __syncthreads();
#pragma unroll
  for (int j = 0; j < 4; ++j)
#pragma unroll
    for (int i = 0; i < 4; ++i) Fb[wch][e0 + j][c0 + i] = acc[j][i];

  for (int h = 0; h < 2; ++h) {
    for (int i = t; i < 64 * 64; i += 512)
      ((float*)Wb)[i] = W3[(i >> 6) * 128 + h * 64 + (i & 63)];
    if (t < 64) Wb[67][t] = b3[h * 64 + t];
    __syncthreads();
    mlp_layer(Fb[wch], Wb, 64, e0, c0, acc);
#pragma unroll
    for (int i = 0; i < 4; ++i) {
      float v = fmaxf(fmaxf(acc[0][i], acc[1][i]), fmaxf(acc[2][i], acc[3][i]));
      Pb[wch][tt >> 4][c0 + i] = v;
    }
    __syncthreads();
    if (tt < 64) {
      float v = Pb[wch][0][tt];
#pragma unroll
      for (int r = 1; r < 16; ++r) v = fmaxf(v, Pb[wch][r][tt]);
      out[(m0 + wch) * F_OUT + h * 64 + tt] = v;
    }
    __syncthreads();
  }
}

// ---------------------------------------------------------------------------
extern "C" void kernel_launch(void* const* d_in, const int* in_sizes, int n_in,
                              void* d_out, int out_size, void* d_ws, size_t ws_size,
                              hipStream_t stream) {
  const float* x   = (const float*)d_in[0];
  const float* pos = (const float*)d_in[1];
  const float* W1 = (const float*)d_in[3];
  const float* b1 = (const float*)d_in[4];
  const float* W2 = (const float*)d_in[5];
  const float* b2 = (const float*)d_in[6];
  const float* W3 = (const float*)d_in[7];
  const float* b3 = (const float*)d_in[8];

  float* out     = (float*)d_out;                 // [M,128]
  float* pos_s   = out + M_CTR * F_OUT;           // [M,3]
  float* batch_s = pos_s + M_CTR * 3;             // [M]

  // workspace layout (gxyz offset 16B-aligned)
  int*    idx    = (int*)d_ws;                    // 4096
  int*    nbr    = idx + M_CTR;                   // 4096*64
  float*  bbox   = (float*)(nbr + M_CTR * K_NBR); // 8
  int*    hist   = (int*)(bbox + 8);              // 4096
  int*    cursor = hist + NCELL;                  // 4096
  int*    cellid = cursor + NCELL;                // 16384
  float4* gxyz   = (float4*)(cellid + N_PTS);     // 16384 float4
  float*  gbox   = (float*)(gxyz + N_PTS);        // 256*8

  prep_bbox_kernel<<<1, 1024, 0, stream>>>(pos, bbox, hist);
  prep_cell_kernel<<<N_PTS / 256, 256, 0, stream>>>(pos, bbox, cellid, hist);
  prep_scan_kernel<<<1, 1024, 0, stream>>>(hist, cursor);
  prep_scatter_kernel<<<N_PTS / 256, 256, 0, stream>>>(pos, cellid, cursor, gxyz);
  prep_bktbox_kernel<<<NBKT, 64, 0, stream>>>(gxyz, gbox);
  fps_bucket_kernel<<<1, 512, 0, stream>>>(pos, gxyz, gbox, idx, pos_s, batch_s);
  nbr_kernel<<<M_CTR, 256, 0, stream>>>(pos, idx, nbr);
  mlp_kernel<<<M_CTR / 2, 512, 0, stream>>>(x, pos, nbr, pos_s,
                                            W1, b1, W2, b2, W3, b3, out);
}